// Round 1
// baseline (1708.450 us; speedup 1.0000x reference)
//
#include <hip/hip_runtime.h>
#include <math.h>

// Problem constants (B, C, H, W) = (2, 512, 64, 64); HEADS=8, DHEAD=64, GROUPS=32
#define BB      2
#define CC      512
#define NN_TOK  4096          // H*W
#define HEADS   8
#define DHEAD   64
#define HID     512
#define GROUPS  32
#define CPG     (CC / GROUPS) // 16 channels per group
#define EPS     1e-5f

// ---------------------------------------------------------------------------
// GroupNorm: one block per (batch, group). Group data is contiguous:
// x[b, g*16 .. g*16+15, :] = 65536 floats.
// ---------------------------------------------------------------------------
__global__ __launch_bounds__(256) void gn_kernel(
    const float* __restrict__ x, const float* __restrict__ gamma,
    const float* __restrict__ beta, float* __restrict__ xn) {
  int bg = blockIdx.x;
  int b = bg / GROUPS, g = bg % GROUPS;
  const size_t base = ((size_t)b * CC + (size_t)g * CPG) * NN_TOK;
  const float4* __restrict__ xin4 = (const float4*)(x + base);
  float4* __restrict__ xo4 = (float4*)(xn + base);
  const int nElem4 = CPG * NN_TOK / 4; // 16384
  int t = threadIdx.x;

  float s = 0.f, ss = 0.f;
  for (int i = t; i < nElem4; i += 256) {
    float4 v = xin4[i];
    s  += v.x + v.y + v.z + v.w;
    ss += v.x * v.x + v.y * v.y + v.z * v.z + v.w * v.w;
  }
  // wave reduce (width 64) then cross-wave via LDS
  #pragma unroll
  for (int off = 32; off >= 1; off >>= 1) {
    s  += __shfl_down(s, off, 64);
    ss += __shfl_down(ss, off, 64);
  }
  __shared__ float rs[4], rss[4];
  __shared__ float smu, srstd;
  int wid = t >> 6, lane = t & 63;
  if (lane == 0) { rs[wid] = s; rss[wid] = ss; }
  __syncthreads();
  if (t == 0) {
    float S = 0.f, SS = 0.f;
    #pragma unroll
    for (int w = 0; w < 4; ++w) { S += rs[w]; SS += rss[w]; }
    const float inv_n = 1.0f / (float)(CPG * NN_TOK);
    float mu = S * inv_n;
    float var = SS * inv_n - mu * mu;
    smu = mu;
    srstd = rsqrtf(var + EPS);
  }
  __syncthreads();
  float mu = smu, rstd = srstd;
  for (int i = t; i < nElem4; i += 256) {
    int c_local = i >> 10;            // i / (4096/4)
    int c = g * CPG + c_local;
    float ga = gamma[c] * rstd;
    float be = beta[c] - mu * ga;
    float4 v = xin4[i];
    float4 o;
    o.x = v.x * ga + be;
    o.y = v.y * ga + be;
    o.z = v.z * ga + be;
    o.w = v.w * ga + be;
    xo4[i] = o;
  }
}

// ---------------------------------------------------------------------------
// Batched fp32 GEMM: out[b, m, n] = sum_c w[m, c] * in[b, c, n] + bias[m]
//                                   (+ resid[b, m, n] if resid != nullptr)
// Tile 64(M) x 64(N), K-step 32, 256 threads, 4x4 micro-tile per thread.
// ---------------------------------------------------------------------------
__global__ __launch_bounds__(256) void gemm_kernel(
    const float* __restrict__ in, const float* __restrict__ w,
    const float* __restrict__ bias, const float* __restrict__ resid,
    float* __restrict__ out, int M, int K, int NN) {
  __shared__ __align__(16) float As[32][68]; // [k][m] (transposed from w)
  __shared__ __align__(16) float Bs[32][68]; // [k][n]
  int b  = blockIdx.z;
  int n0 = blockIdx.x * 64, m0 = blockIdx.y * 64;
  const float* __restrict__ inb = in + (size_t)b * K * NN;
  int t = threadIdx.x, tx = t & 15, ty = t >> 4;
  int tx4 = tx * 4, ty4 = ty * 4;
  float acc[4][4] = {};

  for (int kc = 0; kc < K; kc += 32) {
    __syncthreads();
    #pragma unroll
    for (int f = t; f < 2048; f += 256) {
      int mm = f >> 5, kk = f & 31;
      As[kk][mm] = w[(size_t)(m0 + mm) * K + kc + kk];
    }
    #pragma unroll
    for (int f = t; f < 2048; f += 256) {
      int kk = f >> 6, nn = f & 63;
      Bs[kk][nn] = inb[(size_t)(kc + kk) * NN + n0 + nn];
    }
    __syncthreads();
    #pragma unroll 8
    for (int kk = 0; kk < 32; ++kk) {
      float4 a4 = *(const float4*)&As[kk][ty4];
      float4 b4 = *(const float4*)&Bs[kk][tx4];
      float a_[4] = {a4.x, a4.y, a4.z, a4.w};
      float b_[4] = {b4.x, b4.y, b4.z, b4.w};
      #pragma unroll
      for (int r = 0; r < 4; ++r)
        #pragma unroll
        for (int s = 0; s < 4; ++s)
          acc[r][s] += a_[r] * b_[s];
    }
  }

  float* __restrict__ outb = out + (size_t)b * M * NN;
  const float* __restrict__ resb = resid ? resid + (size_t)b * M * NN : nullptr;
  #pragma unroll
  for (int r = 0; r < 4; ++r) {
    int m = m0 + ty4 + r;
    float bv = bias[m];
    float vals[4];
    #pragma unroll
    for (int s = 0; s < 4; ++s) {
      float vv = acc[r][s] + bv;
      if (resb) vv += resb[(size_t)m * NN + n0 + tx4 + s];
      vals[s] = vv;
    }
    *(float4*)&outb[(size_t)m * NN + n0 + tx4] =
        make_float4(vals[0], vals[1], vals[2], vals[3]);
  }
}

// ---------------------------------------------------------------------------
// Flash attention, fp32. One block per (b*h, 64-query tile).
// q,k,v layout: [b, h*64+d, n] (channel-major). Scores scaled by 0.125
// (= DHEAD^-0.5, exact fold of the two DHEAD^-0.25 factors).
// ---------------------------------------------------------------------------
__global__ __launch_bounds__(256) void attn_kernel(
    const float* __restrict__ q, const float* __restrict__ k,
    const float* __restrict__ v, float* __restrict__ o) {
  __shared__ __align__(16) float qs[64][68]; // [i][d]  (transposed on load)
  __shared__ __align__(16) float ks[64][68]; // [d][j]  (natural)
  __shared__ __align__(16) float vs[64][68]; // [j][d]  (transposed on load)
  __shared__ __align__(16) float ps[64][68]; // [i][j]  P tile

  int bh = blockIdx.y;
  int b = bh >> 3, h = bh & 7;
  int i0 = blockIdx.x * 64;
  const size_t cbase = ((size_t)b * HID + (size_t)h * DHEAD) * NN_TOK;
  const float* __restrict__ qp = q + cbase;
  const float* __restrict__ kp = k + cbase;
  const float* __restrict__ vp = v + cbase;
  int t = threadIdx.x, tx = t & 15, ty = t >> 4;
  int tx4 = tx * 4, ty4 = ty * 4;

  for (int f = t; f < 4096; f += 256) {
    int d = f >> 6, ii = f & 63;
    qs[ii][d] = qp[(size_t)d * NN_TOK + i0 + ii];
  }

  float m_r[4], l_r[4], acc[4][4];
  #pragma unroll
  for (int r = 0; r < 4; ++r) {
    m_r[r] = -1e30f; l_r[r] = 0.f;
    #pragma unroll
    for (int s = 0; s < 4; ++s) acc[r][s] = 0.f;
  }

  for (int jt = 0; jt < NN_TOK / 64; ++jt) {
    int j0 = jt * 64;
    __syncthreads(); // previous-iter consumers done (also covers qs init)
    for (int f = t; f < 4096; f += 256) {
      int d = f >> 6, jj = f & 63;
      float kv = kp[(size_t)d * NN_TOK + j0 + jj];
      float vv = vp[(size_t)d * NN_TOK + j0 + jj];
      ks[d][jj] = kv;
      vs[jj][d] = vv;
    }
    __syncthreads();

    // S tile: rows i = ty4+r, cols j = tx4+s
    float sc[4][4] = {};
    #pragma unroll 4
    for (int d = 0; d < 64; d += 4) {
      float ar[4][4], bc[4][4];
      #pragma unroll
      for (int r = 0; r < 4; ++r) {
        float4 t4 = *(const float4*)&qs[ty4 + r][d];
        ar[r][0] = t4.x; ar[r][1] = t4.y; ar[r][2] = t4.z; ar[r][3] = t4.w;
      }
      #pragma unroll
      for (int kk = 0; kk < 4; ++kk) {
        float4 t4 = *(const float4*)&ks[d + kk][tx4];
        bc[kk][0] = t4.x; bc[kk][1] = t4.y; bc[kk][2] = t4.z; bc[kk][3] = t4.w;
      }
      #pragma unroll
      for (int r = 0; r < 4; ++r)
        #pragma unroll
        for (int s = 0; s < 4; ++s)
          sc[r][s] += ar[r][0] * bc[0][s] + ar[r][1] * bc[1][s]
                    + ar[r][2] * bc[2][s] + ar[r][3] * bc[3][s];
    }

    // online softmax per row; row stats reduced over the 16 lanes (same wave)
    #pragma unroll
    for (int r = 0; r < 4; ++r) {
      #pragma unroll
      for (int s = 0; s < 4; ++s) sc[r][s] *= 0.125f;
      float tm = fmaxf(fmaxf(sc[r][0], sc[r][1]), fmaxf(sc[r][2], sc[r][3]));
      #pragma unroll
      for (int off = 8; off >= 1; off >>= 1)
        tm = fmaxf(tm, __shfl_xor(tm, off, 16));
      float mn = fmaxf(m_r[r], tm);
      float al = __expf(m_r[r] - mn);
      float psum = 0.f;
      #pragma unroll
      for (int s = 0; s < 4; ++s) {
        sc[r][s] = __expf(sc[r][s] - mn);
        psum += sc[r][s];
      }
      #pragma unroll
      for (int off = 8; off >= 1; off >>= 1)
        psum += __shfl_xor(psum, off, 16);
      l_r[r] = l_r[r] * al + psum;
      m_r[r] = mn;
      #pragma unroll
      for (int s = 0; s < 4; ++s) acc[r][s] *= al;
      *(float4*)&ps[ty4 + r][tx4] = make_float4(sc[r][0], sc[r][1], sc[r][2], sc[r][3]);
    }
    __syncthreads();

    // PV: acc[i=ty4+r][d=tx4+s] += sum_j P[i][j] * V[j][d]
    #pragma unroll 4
    for (int j = 0; j < 64; j += 4) {
      float pr[4][4], vc[4][4];
      #pragma unroll
      for (int r = 0; r < 4; ++r) {
        float4 t4 = *(const float4*)&ps[ty4 + r][j];
        pr[r][0] = t4.x; pr[r][1] = t4.y; pr[r][2] = t4.z; pr[r][3] = t4.w;
      }
      #pragma unroll
      for (int kk = 0; kk < 4; ++kk) {
        float4 t4 = *(const float4*)&vs[j + kk][tx4];
        vc[kk][0] = t4.x; vc[kk][1] = t4.y; vc[kk][2] = t4.z; vc[kk][3] = t4.w;
      }
      #pragma unroll
      for (int r = 0; r < 4; ++r)
        #pragma unroll
        for (int s = 0; s < 4; ++s)
          acc[r][s] += pr[r][0] * vc[0][s] + pr[r][1] * vc[1][s]
                     + pr[r][2] * vc[2][s] + pr[r][3] * vc[3][s];
    }
  }

  // epilogue: stage [d][i] in ks for coalesced channel-major store
  __syncthreads();
  #pragma unroll
  for (int r = 0; r < 4; ++r) {
    float inv = 1.0f / l_r[r];
    #pragma unroll
    for (int s = 0; s < 4; ++s)
      ks[tx4 + s][ty4 + r] = acc[r][s] * inv;
  }
  __syncthreads();
  float* __restrict__ op = o + cbase;
  for (int f = t; f < 4096; f += 256) {
    int d = f >> 6, ii = f & 63;
    op[(size_t)d * NN_TOK + i0 + ii] = ks[d][ii];
  }
}

// ---------------------------------------------------------------------------
extern "C" void kernel_launch(void* const* d_in, const int* in_sizes, int n_in,
                              void* d_out, int out_size, void* d_ws, size_t ws_size,
                              hipStream_t stream) {
  const float* x     = (const float*)d_in[0];
  const float* gamma = (const float*)d_in[1];
  const float* beta  = (const float*)d_in[2];
  const float* wq    = (const float*)d_in[3];
  const float* bq    = (const float*)d_in[4];
  const float* wk    = (const float*)d_in[5];
  const float* bk    = (const float*)d_in[6];
  const float* wv    = (const float*)d_in[7];
  const float* bv    = (const float*)d_in[8];
  const float* wo    = (const float*)d_in[9];
  const float* bo    = (const float*)d_in[10];
  float* out = (float*)d_out;
  float* ws  = (float*)d_ws;

  const size_t SZ = (size_t)BB * CC * NN_TOK; // 4,194,304 floats = 16 MiB
  float* xn = ws;            // normalized input
  float* qb = ws + 1 * SZ;
  float* kb = ws + 2 * SZ;
  float* vb = ws + 3 * SZ;
  float* ao = ws + 4 * SZ;   // attention output (pre out-proj); total 80 MiB

  gn_kernel<<<dim3(BB * GROUPS), dim3(256), 0, stream>>>(x, gamma, beta, xn);

  dim3 gg(NN_TOK / 64, HID / 64, BB);
  gemm_kernel<<<gg, dim3(256), 0, stream>>>(xn, wq, bq, nullptr, qb, HID, CC, NN_TOK);
  gemm_kernel<<<gg, dim3(256), 0, stream>>>(xn, wk, bk, nullptr, kb, HID, CC, NN_TOK);
  gemm_kernel<<<gg, dim3(256), 0, stream>>>(xn, wv, bv, nullptr, vb, HID, CC, NN_TOK);

  attn_kernel<<<dim3(NN_TOK / 64, BB * HEADS), dim3(256), 0, stream>>>(qb, kb, vb, ao);

  gemm_kernel<<<dim3(NN_TOK / 64, CC / 64, BB), dim3(256), 0, stream>>>(
      ao, wo, bo, x, out, CC, HID, NN_TOK);
}

// Round 2
// 541.631 us; speedup vs baseline: 3.1543x; 3.1543x over previous
//
#include <hip/hip_runtime.h>
#include <math.h>

#define BB      2
#define CC      512
#define NN_TOK  4096
#define HEADS   8
#define DHEAD   64
#define HID     512
#define GROUPS  32
#define CPG     (CC / GROUPS)
#define EPS     1e-5f

typedef __bf16 bf16x8 __attribute__((ext_vector_type(8)));
typedef float  f32x16 __attribute__((ext_vector_type(16)));

static __device__ __forceinline__ unsigned short f2bf(float f) {
  __bf16 h = (__bf16)f;
  return __builtin_bit_cast(unsigned short, h);
}

// ---------------------------------------------------------------------------
// GroupNorm (unchanged from round 1)
// ---------------------------------------------------------------------------
__global__ __launch_bounds__(256) void gn_kernel(
    const float* __restrict__ x, const float* __restrict__ gamma,
    const float* __restrict__ beta, float* __restrict__ xn) {
  int bg = blockIdx.x;
  int b = bg / GROUPS, g = bg % GROUPS;
  const size_t base = ((size_t)b * CC + (size_t)g * CPG) * NN_TOK;
  const float4* __restrict__ xin4 = (const float4*)(x + base);
  float4* __restrict__ xo4 = (float4*)(xn + base);
  const int nElem4 = CPG * NN_TOK / 4;
  int t = threadIdx.x;

  float s = 0.f, ss = 0.f;
  for (int i = t; i < nElem4; i += 256) {
    float4 v = xin4[i];
    s  += v.x + v.y + v.z + v.w;
    ss += v.x * v.x + v.y * v.y + v.z * v.z + v.w * v.w;
  }
  #pragma unroll
  for (int off = 32; off >= 1; off >>= 1) {
    s  += __shfl_down(s, off, 64);
    ss += __shfl_down(ss, off, 64);
  }
  __shared__ float rs[4], rss[4];
  __shared__ float smu, srstd;
  int wid = t >> 6, lane = t & 63;
  if (lane == 0) { rs[wid] = s; rss[wid] = ss; }
  __syncthreads();
  if (t == 0) {
    float S = 0.f, SS = 0.f;
    #pragma unroll
    for (int w = 0; w < 4; ++w) { S += rs[w]; SS += rss[w]; }
    const float inv_n = 1.0f / (float)(CPG * NN_TOK);
    float mu = S * inv_n;
    float var = SS * inv_n - mu * mu;
    smu = mu;
    srstd = rsqrtf(var + EPS);
  }
  __syncthreads();
  float mu = smu, rstd = srstd;
  for (int i = t; i < nElem4; i += 256) {
    int c_local = i >> 10;
    int c = g * CPG + c_local;
    float ga = gamma[c] * rstd;
    float be = beta[c] - mu * ga;
    float4 v = xin4[i];
    float4 o;
    o.x = v.x * ga + be;
    o.y = v.y * ga + be;
    o.z = v.z * ga + be;
    o.w = v.w * ga + be;
    xo4[i] = o;
  }
}

// ---------------------------------------------------------------------------
// fp32 GEMM (used for final out-proj with residual).
// out[b,m,n] = sum_c w[m,c] in[b,c,n] + bias[m] (+resid)
// ---------------------------------------------------------------------------
__global__ __launch_bounds__(256) void gemm_kernel(
    const float* __restrict__ in, const float* __restrict__ w,
    const float* __restrict__ bias, const float* __restrict__ resid,
    float* __restrict__ out, int M, int K, int NN) {
  __shared__ __align__(16) float As[32][68];
  __shared__ __align__(16) float Bs[32][68];
  int b  = blockIdx.z;
  int n0 = blockIdx.x * 64, m0 = blockIdx.y * 64;
  const float* __restrict__ inb = in + (size_t)b * K * NN;
  int t = threadIdx.x, tx = t & 15, ty = t >> 4;
  int tx4 = tx * 4, ty4 = ty * 4;
  float acc[4][4] = {};

  for (int kc = 0; kc < K; kc += 32) {
    __syncthreads();
    #pragma unroll
    for (int f = t; f < 2048; f += 256) {
      int mm = f >> 5, kk = f & 31;
      As[kk][mm] = w[(size_t)(m0 + mm) * K + kc + kk];
    }
    #pragma unroll
    for (int f = t; f < 2048; f += 256) {
      int kk = f >> 6, nn = f & 63;
      Bs[kk][nn] = inb[(size_t)(kc + kk) * NN + n0 + nn];
    }
    __syncthreads();
    #pragma unroll 8
    for (int kk = 0; kk < 32; ++kk) {
      float4 a4 = *(const float4*)&As[kk][ty4];
      float4 b4 = *(const float4*)&Bs[kk][tx4];
      float a_[4] = {a4.x, a4.y, a4.z, a4.w};
      float b_[4] = {b4.x, b4.y, b4.z, b4.w};
      #pragma unroll
      for (int r = 0; r < 4; ++r)
        #pragma unroll
        for (int s = 0; s < 4; ++s)
          acc[r][s] += a_[r] * b_[s];
    }
  }

  float* __restrict__ outb = out + (size_t)b * M * NN;
  const float* __restrict__ resb = resid ? resid + (size_t)b * M * NN : nullptr;
  #pragma unroll
  for (int r = 0; r < 4; ++r) {
    int m = m0 + ty4 + r;
    float bv = bias[m];
    float vals[4];
    #pragma unroll
    for (int s = 0; s < 4; ++s) {
      float vv = acc[r][s] + bv;
      if (resb) vv += resb[(size_t)m * NN + n0 + tx4 + s];
      vals[s] = vv;
    }
    *(float4*)&outb[(size_t)m * NN + n0 + tx4] =
        make_float4(vals[0], vals[1], vals[2], vals[3]);
  }
}

// ---------------------------------------------------------------------------
// fp32 GEMM -> bf16 TRANSPOSED output qT/kT[(b*8+h)*4096 + n][d], d=m&63.
// scale folded in (Q gets 0.125*log2e). LDS transpose epilogue, b128 stores.
// ---------------------------------------------------------------------------
__global__ __launch_bounds__(256) void gemm_bf16T_kernel(
    const float* __restrict__ in, const float* __restrict__ w,
    const float* __restrict__ bias, unsigned short* __restrict__ outT,
    float scale) {
  const int K = CC, NN = NN_TOK;
  __shared__ __align__(16) float As[32][68];
  __shared__ __align__(16) float Bs[32][68];
  __shared__ __align__(16) unsigned short ot[64 * 72]; // [n][d]
  int b  = blockIdx.z;
  int n0 = blockIdx.x * 64, m0 = blockIdx.y * 64;
  const float* __restrict__ inb = in + (size_t)b * K * NN;
  int t = threadIdx.x, tx = t & 15, ty = t >> 4;
  int tx4 = tx * 4, ty4 = ty * 4;
  float acc[4][4] = {};

  for (int kc = 0; kc < K; kc += 32) {
    __syncthreads();
    #pragma unroll
    for (int f = t; f < 2048; f += 256) {
      int mm = f >> 5, kk = f & 31;
      As[kk][mm] = w[(size_t)(m0 + mm) * K + kc + kk];
    }
    #pragma unroll
    for (int f = t; f < 2048; f += 256) {
      int kk = f >> 6, nn = f & 63;
      Bs[kk][nn] = inb[(size_t)(kc + kk) * NN + n0 + nn];
    }
    __syncthreads();
    #pragma unroll 8
    for (int kk = 0; kk < 32; ++kk) {
      float4 a4 = *(const float4*)&As[kk][ty4];
      float4 b4 = *(const float4*)&Bs[kk][tx4];
      float a_[4] = {a4.x, a4.y, a4.z, a4.w};
      float b_[4] = {b4.x, b4.y, b4.z, b4.w};
      #pragma unroll
      for (int r = 0; r < 4; ++r)
        #pragma unroll
        for (int s = 0; s < 4; ++s)
          acc[r][s] += a_[r] * b_[s];
    }
  }

  #pragma unroll
  for (int r = 0; r < 4; ++r) {
    float bv = bias[m0 + ty4 + r];
    #pragma unroll
    for (int s = 0; s < 4; ++s)
      ot[(tx4 + s) * 72 + ty4 + r] = f2bf((acc[r][s] + bv) * scale);
  }
  __syncthreads();
  int h = m0 >> 6;
  const size_t tbase = ((size_t)(b * HEADS + h) * NN_TOK + n0);
  #pragma unroll
  for (int f = t; f < 512; f += 256) {
    int n = f >> 3, c = (f & 7) * 8;
    *(uint4*)&outT[(tbase + n) * DHEAD + c] = *(const uint4*)&ot[n * 72 + c];
  }
}

// ---------------------------------------------------------------------------
// fp32 GEMM -> bf16 natural-layout output (V): vb[b,m,n]
// ---------------------------------------------------------------------------
__global__ __launch_bounds__(256) void gemm_bf16N_kernel(
    const float* __restrict__ in, const float* __restrict__ w,
    const float* __restrict__ bias, unsigned short* __restrict__ outb) {
  const int K = CC, NN = NN_TOK, M = HID;
  __shared__ __align__(16) float As[32][68];
  __shared__ __align__(16) float Bs[32][68];
  int b  = blockIdx.z;
  int n0 = blockIdx.x * 64, m0 = blockIdx.y * 64;
  const float* __restrict__ inb = in + (size_t)b * K * NN;
  int t = threadIdx.x, tx = t & 15, ty = t >> 4;
  int tx4 = tx * 4, ty4 = ty * 4;
  float acc[4][4] = {};

  for (int kc = 0; kc < K; kc += 32) {
    __syncthreads();
    #pragma unroll
    for (int f = t; f < 2048; f += 256) {
      int mm = f >> 5, kk = f & 31;
      As[kk][mm] = w[(size_t)(m0 + mm) * K + kc + kk];
    }
    #pragma unroll
    for (int f = t; f < 2048; f += 256) {
      int kk = f >> 6, nn = f & 63;
      Bs[kk][nn] = inb[(size_t)(kc + kk) * NN + n0 + nn];
    }
    __syncthreads();
    #pragma unroll 8
    for (int kk = 0; kk < 32; ++kk) {
      float4 a4 = *(const float4*)&As[kk][ty4];
      float4 b4 = *(const float4*)&Bs[kk][tx4];
      float a_[4] = {a4.x, a4.y, a4.z, a4.w};
      float b_[4] = {b4.x, b4.y, b4.z, b4.w};
      #pragma unroll
      for (int r = 0; r < 4; ++r)
        #pragma unroll
        for (int s = 0; s < 4; ++s)
          acc[r][s] += a_[r] * b_[s];
    }
  }

  unsigned short* __restrict__ ob = outb + (size_t)b * M * NN;
  #pragma unroll
  for (int r = 0; r < 4; ++r) {
    int m = m0 + ty4 + r;
    float bv = bias[m];
    ushort4 pk;
    pk.x = f2bf(acc[r][0] + bv);
    pk.y = f2bf(acc[r][1] + bv);
    pk.z = f2bf(acc[r][2] + bv);
    pk.w = f2bf(acc[r][3] + bv);
    *(ushort4*)&ob[(size_t)m * NN + n0 + tx4] = pk;
  }
}

// ---------------------------------------------------------------------------
// MFMA flash attention.
// qT,kT: [b,h,tok,d] bf16 (Q pre-scaled by 0.125*log2e). v: [b,h*64+d,tok] bf16.
// Computes S^T = K·Q^T via 32x32x16 MFMA; online softmax per i-column
// (per-lane scalar m/l); O^T = V^T·P^T; writes ao [b, h*64+d, tok] fp32.
// Block: 256 thr = 4 waves; i-block 128 (wave owns 32 queries); j-tile 64.
// ---------------------------------------------------------------------------
__global__ __launch_bounds__(256) void attn_mfma_kernel(
    const unsigned short* __restrict__ qT, const unsigned short* __restrict__ kT,
    const unsigned short* __restrict__ vv, float* __restrict__ ao) {
  __shared__ __align__(16) unsigned short ks[64 * 72];      // [j][d]
  __shared__ __align__(16) unsigned short vs[64 * 72];      // [d][j]
  __shared__ __align__(16) unsigned short ps[4 * 32 * 72];  // per-wave [i][j]
  int bh = blockIdx.y;
  int i0 = blockIdx.x * 128;
  const size_t hb = (size_t)bh * NN_TOK;
  const unsigned short* __restrict__ qtg = qT + hb * DHEAD;
  const unsigned short* __restrict__ ktg = kT + hb * DHEAD;
  const unsigned short* __restrict__ vg  = vv + hb * DHEAD; // == (bh*64)*4096
  float* __restrict__ aog = ao + hb * DHEAD;
  int t = threadIdx.x;
  int w = t >> 6, lane = t & 63, l31 = lane & 31, q1 = lane >> 5;

  // preload Q B-fragments for this wave's 32-query strip (registers, whole kernel)
  int irow = i0 + w * 32 + l31;
  bf16x8 qf[4];
  #pragma unroll
  for (int s = 0; s < 4; ++s)
    qf[s] = *(const bf16x8*)&qtg[(size_t)irow * DHEAD + s * 16 + q1 * 8];

  f32x16 o0 = {0,0,0,0,0,0,0,0,0,0,0,0,0,0,0,0};
  f32x16 o1 = {0,0,0,0,0,0,0,0,0,0,0,0,0,0,0,0};
  float mrun = -1e30f, lrun = 0.f;
  unsigned short* __restrict__ psw = ps + w * 32 * 72;

  for (int jt = 0; jt < NN_TOK / 64; ++jt) {
    int j0 = jt * 64;
    __syncthreads();
    #pragma unroll
    for (int f = t; f < 512; f += 256) {
      int row = f >> 3, c = (f & 7) * 8;
      *(uint4*)&ks[row * 72 + c] = *(const uint4*)&ktg[(size_t)(j0 + row) * DHEAD + c];
      *(uint4*)&vs[row * 72 + c] = *(const uint4*)&vg[(size_t)row * NN_TOK + j0 + c];
    }
    __syncthreads();

    // S^T[j][i] = sum_d K[j][d] * Q[i][d]
    f32x16 s0 = {0,0,0,0,0,0,0,0,0,0,0,0,0,0,0,0};
    f32x16 s1 = {0,0,0,0,0,0,0,0,0,0,0,0,0,0,0,0};
    #pragma unroll
    for (int s = 0; s < 4; ++s) {
      bf16x8 a0 = *(const bf16x8*)&ks[l31 * 72 + s * 16 + q1 * 8];
      bf16x8 a1 = *(const bf16x8*)&ks[(32 + l31) * 72 + s * 16 + q1 * 8];
      s0 = __builtin_amdgcn_mfma_f32_32x32x16_bf16(a0, qf[s], s0, 0, 0, 0);
      s1 = __builtin_amdgcn_mfma_f32_32x32x16_bf16(a1, qf[s], s1, 0, 0, 0);
    }

    // per-lane: one i-column (col=lane&31), 32 j's across regs + q1 partner
    float tm = -1e30f;
    #pragma unroll
    for (int r = 0; r < 16; ++r) tm = fmaxf(tm, fmaxf(s0[r], s1[r]));
    tm = fmaxf(tm, __shfl_xor(tm, 32));
    float mnew = fmaxf(mrun, tm);
    float alpha = __builtin_amdgcn_exp2f(mrun - mnew);
    float psum = 0.f;
    #pragma unroll
    for (int jm = 0; jm < 2; ++jm) {
      #pragma unroll
      for (int g = 0; g < 4; ++g) {
        float p0, p1, p2, p3;
        if (jm == 0) {
          p0 = __builtin_amdgcn_exp2f(s0[4 * g + 0] - mnew);
          p1 = __builtin_amdgcn_exp2f(s0[4 * g + 1] - mnew);
          p2 = __builtin_amdgcn_exp2f(s0[4 * g + 2] - mnew);
          p3 = __builtin_amdgcn_exp2f(s0[4 * g + 3] - mnew);
        } else {
          p0 = __builtin_amdgcn_exp2f(s1[4 * g + 0] - mnew);
          p1 = __builtin_amdgcn_exp2f(s1[4 * g + 1] - mnew);
          p2 = __builtin_amdgcn_exp2f(s1[4 * g + 2] - mnew);
          p3 = __builtin_amdgcn_exp2f(s1[4 * g + 3] - mnew);
        }
        psum += (p0 + p1) + (p2 + p3);
        ushort4 pk;
        pk.x = f2bf(p0); pk.y = f2bf(p1); pk.z = f2bf(p2); pk.w = f2bf(p3);
        // j = jm*32 + 8g + 4*q1 + c  (C-layout row map), i row = l31
        *(ushort4*)&psw[l31 * 72 + jm * 32 + g * 8 + q1 * 4] = pk;
      }
    }
    psum += __shfl_xor(psum, 32);
    lrun = lrun * alpha + psum;
    mrun = mnew;
    #pragma unroll
    for (int r = 0; r < 16; ++r) { o0[r] *= alpha; o1[r] *= alpha; }

    // O^T[d][i] += sum_j V^T[d][j] * P^T[j][i]
    #pragma unroll
    for (int s = 0; s < 4; ++s) {
      bf16x8 pb  = *(const bf16x8*)&psw[l31 * 72 + s * 16 + q1 * 8];
      bf16x8 va0 = *(const bf16x8*)&vs[l31 * 72 + s * 16 + q1 * 8];
      bf16x8 va1 = *(const bf16x8*)&vs[(32 + l31) * 72 + s * 16 + q1 * 8];
      o0 = __builtin_amdgcn_mfma_f32_32x32x16_bf16(va0, pb, o0, 0, 0, 0);
      o1 = __builtin_amdgcn_mfma_f32_32x32x16_bf16(va1, pb, o1, 0, 0, 0);
    }
  }

  // epilogue: O^T C-layout -> ao[d][i], coalesced 128B segments per q1-half
  float inv = 1.0f / lrun;
  #pragma unroll
  for (int dm = 0; dm < 2; ++dm) {
    #pragma unroll
    for (int r = 0; r < 16; ++r) {
      int d = dm * 32 + (r & 3) + 8 * (r >> 2) + 4 * q1;
      float val = (dm == 0 ? o0[r] : o1[r]) * inv;
      aog[(size_t)d * NN_TOK + i0 + w * 32 + l31] = val;
    }
  }
}

// ---------------------------------------------------------------------------
extern "C" void kernel_launch(void* const* d_in, const int* in_sizes, int n_in,
                              void* d_out, int out_size, void* d_ws, size_t ws_size,
                              hipStream_t stream) {
  const float* x     = (const float*)d_in[0];
  const float* gamma = (const float*)d_in[1];
  const float* beta  = (const float*)d_in[2];
  const float* wq    = (const float*)d_in[3];
  const float* bq    = (const float*)d_in[4];
  const float* wk    = (const float*)d_in[5];
  const float* bk    = (const float*)d_in[6];
  const float* wv    = (const float*)d_in[7];
  const float* bv    = (const float*)d_in[8];
  const float* wo    = (const float*)d_in[9];
  const float* bo    = (const float*)d_in[10];
  float* out = (float*)d_out;

  const size_t SZ = (size_t)BB * CC * NN_TOK; // 4,194,304 elements
  float* xn = (float*)d_ws;                                  // 16 MB fp32
  unsigned short* qT = (unsigned short*)(xn + SZ);           // 8 MB bf16 [b,h,tok,d]
  unsigned short* kT = qT + SZ;                              // 8 MB bf16 [b,h,tok,d]
  unsigned short* vB = kT + SZ;                              // 8 MB bf16 [b,c,tok]
  float* ao = (float*)(vB + SZ);                             // 16 MB fp32 [b,c,tok]

  gn_kernel<<<dim3(BB * GROUPS), dim3(256), 0, stream>>>(x, gamma, beta, xn);

  const float QSCALE = 0.125f * 1.44269504088896340736f; // d^-0.5 * log2(e)
  dim3 gg(NN_TOK / 64, HID / 64, BB);
  gemm_bf16T_kernel<<<gg, dim3(256), 0, stream>>>(xn, wq, bq, qT, QSCALE);
  gemm_bf16T_kernel<<<gg, dim3(256), 0, stream>>>(xn, wk, bk, kT, 1.0f);
  gemm_bf16N_kernel<<<gg, dim3(256), 0, stream>>>(xn, wv, bv, vB);

  attn_mfma_kernel<<<dim3(NN_TOK / 128, BB * HEADS), dim3(256), 0, stream>>>(
      qT, kT, vB, ao);

  gemm_kernel<<<dim3(NN_TOK / 64, CC / 64, BB), dim3(256), 0, stream>>>(
      ao, wo, bo, x, out, CC, HID, NN_TOK);
}

// Round 3
// 285.182 us; speedup vs baseline: 5.9907x; 1.8992x over previous
//
#include <hip/hip_runtime.h>
#include <math.h>

#define BB      2
#define CC      512
#define NN_TOK  4096
#define HEADS   8
#define DHEAD   64
#define HID     512
#define GROUPS  32
#define CPG     (CC / GROUPS)
#define EPS     1e-5f

typedef __bf16 bf16x8 __attribute__((ext_vector_type(8)));
typedef float  f32x4  __attribute__((ext_vector_type(4)));
typedef float  f32x16 __attribute__((ext_vector_type(16)));

static __device__ __forceinline__ unsigned short f2bf(float f) {
  __bf16 h = (__bf16)f;
  return __builtin_bit_cast(unsigned short, h);
}

// ---------------------------------------------------------------------------
// Convert 4 fp32 512x512 weights to bf16. grid (128, 4), 256 thr, 8 elem/thr.
// ---------------------------------------------------------------------------
__global__ __launch_bounds__(256) void wconv_kernel(
    const float* __restrict__ w0, const float* __restrict__ w1,
    const float* __restrict__ w2, const float* __restrict__ w3,
    unsigned short* __restrict__ o0, unsigned short* __restrict__ o1,
    unsigned short* __restrict__ o2, unsigned short* __restrict__ o3) {
  int y = blockIdx.y;
  const float* src = (y == 0) ? w0 : (y == 1) ? w1 : (y == 2) ? w2 : w3;
  unsigned short* dst = (y == 0) ? o0 : (y == 1) ? o1 : (y == 2) ? o2 : o3;
  int idx = (blockIdx.x * 256 + threadIdx.x) * 8;
  float4 a = *(const float4*)&src[idx];
  float4 b = *(const float4*)&src[idx + 4];
  ushort4 p0, p1;
  p0.x = f2bf(a.x); p0.y = f2bf(a.y); p0.z = f2bf(a.z); p0.w = f2bf(a.w);
  p1.x = f2bf(b.x); p1.y = f2bf(b.y); p1.z = f2bf(b.z); p1.w = f2bf(b.w);
  *(ushort4*)&dst[idx] = p0;
  *(ushort4*)&dst[idx + 4] = p1;
}

// ---------------------------------------------------------------------------
// GroupNorm -> bf16 [b][c][tok]
// ---------------------------------------------------------------------------
__global__ __launch_bounds__(256) void gn_kernel(
    const float* __restrict__ x, const float* __restrict__ gamma,
    const float* __restrict__ beta, unsigned short* __restrict__ xnb) {
  int bg = blockIdx.x;
  int b = bg / GROUPS, g = bg % GROUPS;
  const size_t base = ((size_t)b * CC + (size_t)g * CPG) * NN_TOK;
  const float4* __restrict__ xin4 = (const float4*)(x + base);
  unsigned short* __restrict__ xo = xnb + base;
  const int nElem4 = CPG * NN_TOK / 4;
  int t = threadIdx.x;

  float s = 0.f, ss = 0.f;
  for (int i = t; i < nElem4; i += 256) {
    float4 v = xin4[i];
    s  += v.x + v.y + v.z + v.w;
    ss += v.x * v.x + v.y * v.y + v.z * v.z + v.w * v.w;
  }
  #pragma unroll
  for (int off = 32; off >= 1; off >>= 1) {
    s  += __shfl_down(s, off, 64);
    ss += __shfl_down(ss, off, 64);
  }
  __shared__ float rs[4], rss[4];
  __shared__ float smu, srstd;
  int wid = t >> 6, lane = t & 63;
  if (lane == 0) { rs[wid] = s; rss[wid] = ss; }
  __syncthreads();
  if (t == 0) {
    float S = 0.f, SS = 0.f;
    #pragma unroll
    for (int w = 0; w < 4; ++w) { S += rs[w]; SS += rss[w]; }
    const float inv_n = 1.0f / (float)(CPG * NN_TOK);
    float mu = S * inv_n;
    float var = SS * inv_n - mu * mu;
    smu = mu;
    srstd = rsqrtf(var + EPS);
  }
  __syncthreads();
  float mu = smu, rstd = srstd;
  const int nElem8 = CPG * NN_TOK / 8;   // 8192
  for (int f = t; f < nElem8; f += 256) {
    int c_local = f >> 9;                 // f / (4096/8)
    int c = g * CPG + c_local;
    float ga = gamma[c] * rstd;
    float be = beta[c] - mu * ga;
    float4 a = xin4[2 * f];
    float4 d = xin4[2 * f + 1];
    ushort4 p0, p1;
    p0.x = f2bf(a.x * ga + be); p0.y = f2bf(a.y * ga + be);
    p0.z = f2bf(a.z * ga + be); p0.w = f2bf(a.w * ga + be);
    p1.x = f2bf(d.x * ga + be); p1.y = f2bf(d.y * ga + be);
    p1.z = f2bf(d.z * ga + be); p1.w = f2bf(d.w * ga + be);
    *(ushort4*)&xo[f * 8] = p0;
    *(ushort4*)&xo[f * 8 + 4] = p1;
  }
}

// ---------------------------------------------------------------------------
// Transpose bf16 [b][c 512][tok 4096] -> [b][tok][c]. 64x64 tiles.
// grid (64, 8, 2), 256 thr.
// ---------------------------------------------------------------------------
__global__ __launch_bounds__(256) void transpose_kernel(
    const unsigned short* __restrict__ in, unsigned short* __restrict__ outT) {
  __shared__ __align__(16) unsigned short lds[64 * 72];
  int b = blockIdx.z;
  int t0 = blockIdx.x * 64, c0 = blockIdx.y * 64;
  const unsigned short* __restrict__ inb = in + (size_t)b * CC * NN_TOK;
  unsigned short* __restrict__ ob = outT + (size_t)b * NN_TOK * CC;
  int t = threadIdx.x;
  #pragma unroll
  for (int i = 0; i < 2; ++i) {
    int f = t + i * 256;
    int row = f >> 3, ch = f & 7;  // row = c_local
    *(uint4*)&lds[row * 72 + ch * 8] =
        *(const uint4*)&inb[(size_t)(c0 + row) * NN_TOK + t0 + ch * 8];
  }
  __syncthreads();
  #pragma unroll
  for (int i = 0; i < 2; ++i) {
    int f = t + i * 256;
    int row = f >> 3, ch = f & 7;  // row = tok_local
    ushort4 a, b4;
    a.x  = lds[(ch * 8 + 0) * 72 + row];
    a.y  = lds[(ch * 8 + 1) * 72 + row];
    a.z  = lds[(ch * 8 + 2) * 72 + row];
    a.w  = lds[(ch * 8 + 3) * 72 + row];
    b4.x = lds[(ch * 8 + 4) * 72 + row];
    b4.y = lds[(ch * 8 + 5) * 72 + row];
    b4.z = lds[(ch * 8 + 6) * 72 + row];
    b4.w = lds[(ch * 8 + 7) * 72 + row];
    *(ushort4*)&ob[(size_t)(t0 + row) * CC + c0 + ch * 8] = a;
    *(ushort4*)&ob[(size_t)(t0 + row) * CC + c0 + ch * 8 + 4] = b4;
  }
}

// ---------------------------------------------------------------------------
// Fused Q/K/V MFMA GEMM. out = W(512x512 bf16) * xn^T + bias.
// B operand: xnT [b][tok][c] bf16. blockIdx.y: 0-3 Q, 4-7 K, 8-11 V.
// Tile 128(m) x 128(n), K=512, BK=64. 4 waves, wave tile 64x64 (4x4 of 16x16).
// Q/K: LDS-transposed epilogue -> [b,h,tok,d] bf16 (Q scaled). V: [b,c,tok].
// ---------------------------------------------------------------------------
__global__ __launch_bounds__(256) void qkv_gemm_kernel(
    const unsigned short* __restrict__ xnT,
    const unsigned short* __restrict__ wqb, const unsigned short* __restrict__ wkb,
    const unsigned short* __restrict__ wvb,
    const float* __restrict__ bq, const float* __restrict__ bk,
    const float* __restrict__ bv,
    unsigned short* __restrict__ qT, unsigned short* __restrict__ kT,
    unsigned short* __restrict__ vB) {
  __shared__ __align__(16) unsigned short AsBs[2 * 128 * 72];
  unsigned short* As = AsBs;             // [m 128][k 64 (+8 pad)]
  unsigned short* Bs = AsBs + 128 * 72;  // [n 128][k 64 (+8 pad)]
  int b = blockIdx.z;
  int y = blockIdx.y;
  int which = y >> 2, yl = y & 3;
  const unsigned short* __restrict__ W =
      (which == 0) ? wqb : (which == 1) ? wkb : wvb;
  const float* __restrict__ bias = (which == 0) ? bq : (which == 1) ? bk : bv;
  int m0 = yl * 128;
  int n0 = blockIdx.x * 128;
  const unsigned short* __restrict__ Bsrc = xnT + (size_t)b * NN_TOK * CC;
  int t = threadIdx.x, w = t >> 6, lane = t & 63;
  int wm = (w >> 1) * 64, wn = (w & 1) * 64;
  int l15 = lane & 15, lq = lane >> 4;

  f32x4 acc[4][4];
  #pragma unroll
  for (int mt = 0; mt < 4; ++mt)
    #pragma unroll
    for (int nt = 0; nt < 4; ++nt) acc[mt][nt] = (f32x4){0.f, 0.f, 0.f, 0.f};

  for (int kc = 0; kc < CC; kc += 64) {
    __syncthreads();
    #pragma unroll
    for (int i = 0; i < 4; ++i) {
      int f = t + i * 256;
      int row = f >> 3, ch = f & 7;
      *(uint4*)&As[row * 72 + ch * 8] =
          *(const uint4*)&W[(size_t)(m0 + row) * CC + kc + ch * 8];
      *(uint4*)&Bs[row * 72 + ch * 8] =
          *(const uint4*)&Bsrc[(size_t)(n0 + row) * CC + kc + ch * 8];
    }
    __syncthreads();
    #pragma unroll
    for (int ks = 0; ks < 2; ++ks) {
      bf16x8 af[4], bfr[4];
      #pragma unroll
      for (int i = 0; i < 4; ++i) {
        af[i]  = *(const bf16x8*)&As[(wm + i * 16 + l15) * 72 + ks * 32 + lq * 8];
        bfr[i] = *(const bf16x8*)&Bs[(wn + i * 16 + l15) * 72 + ks * 32 + lq * 8];
      }
      #pragma unroll
      for (int mt = 0; mt < 4; ++mt)
        #pragma unroll
        for (int nt = 0; nt < 4; ++nt)
          acc[mt][nt] = __builtin_amdgcn_mfma_f32_16x16x32_bf16(
              af[mt], bfr[nt], acc[mt][nt], 0, 0, 0);
    }
  }
  __syncthreads();  // before LDS overlay reuse

  if (which < 2) {
    const float sc = (which == 0) ? 0.18033688011112043f : 1.0f; // 0.125*log2e
    unsigned short* __restrict__ dstT = (which == 0) ? qT : kT;
    unsigned short* buf = AsBs + w * 2304;  // per-wave [32 tok][72 d]
    int h = (m0 + wm) >> 6;
    const size_t hbase = (size_t)(b * HEADS + h) * NN_TOK;
    #pragma unroll
    for (int p = 0; p < 2; ++p) {
      #pragma unroll
      for (int mt = 0; mt < 4; ++mt) {
        float4 bv4 = *(const float4*)&bias[m0 + wm + mt * 16 + lq * 4];
        #pragma unroll
        for (int ntl = 0; ntl < 2; ++ntl) {
          int nt = p * 2 + ntl;
          f32x4 a = acc[mt][nt];
          ushort4 pk;
          pk.x = f2bf((a[0] + bv4.x) * sc);
          pk.y = f2bf((a[1] + bv4.y) * sc);
          pk.z = f2bf((a[2] + bv4.z) * sc);
          pk.w = f2bf((a[3] + bv4.w) * sc);
          *(ushort4*)&buf[(ntl * 16 + l15) * 72 + mt * 16 + lq * 4] = pk;
        }
      }
      #pragma unroll
      for (int it = 0; it < 4; ++it) {
        int idx = it * 64 + lane;
        int row = idx >> 3, ch = idx & 7;
        int tok = n0 + wn + p * 32 + row;
        *(uint4*)&dstT[(hbase + tok) * DHEAD + ch * 8] =
            *(const uint4*)&buf[row * 72 + ch * 8];
      }
    }
  } else {
    unsigned short* __restrict__ dst = vB + (size_t)b * HID * NN_TOK;
    #pragma unroll
    for (int mt = 0; mt < 4; ++mt) {
      float4 bv4 = *(const float4*)&bias[m0 + wm + mt * 16 + lq * 4];
      float bvr[4] = {bv4.x, bv4.y, bv4.z, bv4.w};
      #pragma unroll
      for (int nt = 0; nt < 4; ++nt) {
        int tok = n0 + wn + nt * 16 + l15;
        #pragma unroll
        for (int r = 0; r < 4; ++r) {
          int m = m0 + wm + mt * 16 + lq * 4 + r;
          dst[(size_t)m * NN_TOK + tok] = f2bf(acc[mt][nt][r] + bvr[r]);
        }
      }
    }
  }
}

// ---------------------------------------------------------------------------
// Out-proj MFMA GEMM: out[b,c,tok] = wo * ao^T + bo + x (fp32 out, residual).
// B operand: aoT [b][tok][hid] bf16. grid (32, 4, 2).
// ---------------------------------------------------------------------------
__global__ __launch_bounds__(256) void outproj_kernel(
    const unsigned short* __restrict__ aoT, const unsigned short* __restrict__ wob,
    const float* __restrict__ bo, const float* __restrict__ x,
    float* __restrict__ out) {
  __shared__ __align__(16) unsigned short AsBs[2 * 128 * 72];
  unsigned short* As = AsBs;
  unsigned short* Bs = AsBs + 128 * 72;
  int b = blockIdx.z;
  int m0 = blockIdx.y * 128;
  int n0 = blockIdx.x * 128;
  const unsigned short* __restrict__ Bsrc = aoT + (size_t)b * NN_TOK * HID;
  int t = threadIdx.x, w = t >> 6, lane = t & 63;
  int wm = (w >> 1) * 64, wn = (w & 1) * 64;
  int l15 = lane & 15, lq = lane >> 4;

  f32x4 acc[4][4];
  #pragma unroll
  for (int mt = 0; mt < 4; ++mt)
    #pragma unroll
    for (int nt = 0; nt < 4; ++nt) acc[mt][nt] = (f32x4){0.f, 0.f, 0.f, 0.f};

  for (int kc = 0; kc < HID; kc += 64) {
    __syncthreads();
    #pragma unroll
    for (int i = 0; i < 4; ++i) {
      int f = t + i * 256;
      int row = f >> 3, ch = f & 7;
      *(uint4*)&As[row * 72 + ch * 8] =
          *(const uint4*)&wob[(size_t)(m0 + row) * HID + kc + ch * 8];
      *(uint4*)&Bs[row * 72 + ch * 8] =
          *(const uint4*)&Bsrc[(size_t)(n0 + row) * HID + kc + ch * 8];
    }
    __syncthreads();
    #pragma unroll
    for (int ks = 0; ks < 2; ++ks) {
      bf16x8 af[4], bfr[4];
      #pragma unroll
      for (int i = 0; i < 4; ++i) {
        af[i]  = *(const bf16x8*)&As[(wm + i * 16 + l15) * 72 + ks * 32 + lq * 8];
        bfr[i] = *(const bf16x8*)&Bs[(wn + i * 16 + l15) * 72 + ks * 32 + lq * 8];
      }
      #pragma unroll
      for (int mt = 0; mt < 4; ++mt)
        #pragma unroll
        for (int nt = 0; nt < 4; ++nt)
          acc[mt][nt] = __builtin_amdgcn_mfma_f32_16x16x32_bf16(
              af[mt], bfr[nt], acc[mt][nt], 0, 0, 0);
    }
  }

  const float* __restrict__ xb = x + (size_t)b * CC * NN_TOK;
  float* __restrict__ ob = out + (size_t)b * CC * NN_TOK;
  #pragma unroll
  for (int mt = 0; mt < 4; ++mt) {
    float4 bv4 = *(const float4*)&bo[m0 + wm + mt * 16 + lq * 4];
    float bvr[4] = {bv4.x, bv4.y, bv4.z, bv4.w};
    #pragma unroll
    for (int nt = 0; nt < 4; ++nt) {
      int tok = n0 + wn + nt * 16 + l15;
      #pragma unroll
      for (int r = 0; r < 4; ++r) {
        int m = m0 + wm + mt * 16 + lq * 4 + r;
        size_t off = (size_t)m * NN_TOK + tok;
        ob[off] = acc[mt][nt][r] + bvr[r] + xb[off];
      }
    }
  }
}

// ---------------------------------------------------------------------------
// MFMA flash attention (round-2 core). New: epilogue writes aoT bf16
// [b][tok][hid], and alpha-rescale skipped via wave vote when max unchanged.
// ---------------------------------------------------------------------------
__global__ __launch_bounds__(256) void attn_mfma_kernel(
    const unsigned short* __restrict__ qT, const unsigned short* __restrict__ kT,
    const unsigned short* __restrict__ vv, unsigned short* __restrict__ aoT) {
  __shared__ __align__(16) unsigned short ks[64 * 72];      // [j][d]
  __shared__ __align__(16) unsigned short vs[64 * 72];      // [d][j]
  __shared__ __align__(16) unsigned short ps[4 * 32 * 72];  // per-wave [i][j]
  int bh = blockIdx.y;
  int b = bh >> 3, h = bh & 7;
  int i0 = blockIdx.x * 128;
  const size_t hb = (size_t)bh * NN_TOK;
  const unsigned short* __restrict__ qtg = qT + hb * DHEAD;
  const unsigned short* __restrict__ ktg = kT + hb * DHEAD;
  const unsigned short* __restrict__ vg  = vv + hb * DHEAD;
  int t = threadIdx.x;
  int w = t >> 6, lane = t & 63, l31 = lane & 31, q1 = lane >> 5;

  int irow = i0 + w * 32 + l31;
  bf16x8 qf[4];
  #pragma unroll
  for (int s = 0; s < 4; ++s)
    qf[s] = *(const bf16x8*)&qtg[(size_t)irow * DHEAD + s * 16 + q1 * 8];

  f32x16 o0 = {0,0,0,0,0,0,0,0,0,0,0,0,0,0,0,0};
  f32x16 o1 = {0,0,0,0,0,0,0,0,0,0,0,0,0,0,0,0};
  float mrun = -1e30f, lrun = 0.f;
  unsigned short* __restrict__ psw = ps + w * 32 * 72;

  for (int jt = 0; jt < NN_TOK / 64; ++jt) {
    int j0 = jt * 64;
    __syncthreads();
    #pragma unroll
    for (int f = t; f < 512; f += 256) {
      int row = f >> 3, c = (f & 7) * 8;
      *(uint4*)&ks[row * 72 + c] = *(const uint4*)&ktg[(size_t)(j0 + row) * DHEAD + c];
      *(uint4*)&vs[row * 72 + c] = *(const uint4*)&vg[(size_t)row * NN_TOK + j0 + c];
    }
    __syncthreads();

    f32x16 s0 = {0,0,0,0,0,0,0,0,0,0,0,0,0,0,0,0};
    f32x16 s1 = {0,0,0,0,0,0,0,0,0,0,0,0,0,0,0,0};
    #pragma unroll
    for (int s = 0; s < 4; ++s) {
      bf16x8 a0 = *(const bf16x8*)&ks[l31 * 72 + s * 16 + q1 * 8];
      bf16x8 a1 = *(const bf16x8*)&ks[(32 + l31) * 72 + s * 16 + q1 * 8];
      s0 = __builtin_amdgcn_mfma_f32_32x32x16_bf16(a0, qf[s], s0, 0, 0, 0);
      s1 = __builtin_amdgcn_mfma_f32_32x32x16_bf16(a1, qf[s], s1, 0, 0, 0);
    }

    float tm = -1e30f;
    #pragma unroll
    for (int r = 0; r < 16; ++r) tm = fmaxf(tm, fmaxf(s0[r], s1[r]));
    tm = fmaxf(tm, __shfl_xor(tm, 32));
    bool anyup = __any(tm > mrun);
    float mnew = anyup ? fmaxf(mrun, tm) : mrun;
    float alpha = anyup ? __builtin_amdgcn_exp2f(mrun - mnew) : 1.0f;
    float psum = 0.f;
    #pragma unroll
    for (int jm = 0; jm < 2; ++jm) {
      #pragma unroll
      for (int g = 0; g < 4; ++g) {
        float p0, p1, p2, p3;
        if (jm == 0) {
          p0 = __builtin_amdgcn_exp2f(s0[4 * g + 0] - mnew);
          p1 = __builtin_amdgcn_exp2f(s0[4 * g + 1] - mnew);
          p2 = __builtin_amdgcn_exp2f(s0[4 * g + 2] - mnew);
          p3 = __builtin_amdgcn_exp2f(s0[4 * g + 3] - mnew);
        } else {
          p0 = __builtin_amdgcn_exp2f(s1[4 * g + 0] - mnew);
          p1 = __builtin_amdgcn_exp2f(s1[4 * g + 1] - mnew);
          p2 = __builtin_amdgcn_exp2f(s1[4 * g + 2] - mnew);
          p3 = __builtin_amdgcn_exp2f(s1[4 * g + 3] - mnew);
        }
        psum += (p0 + p1) + (p2 + p3);
        ushort4 pk;
        pk.x = f2bf(p0); pk.y = f2bf(p1); pk.z = f2bf(p2); pk.w = f2bf(p3);
        *(ushort4*)&psw[l31 * 72 + jm * 32 + g * 8 + q1 * 4] = pk;
      }
    }
    psum += __shfl_xor(psum, 32);
    lrun = lrun * alpha + psum;
    mrun = mnew;
    if (anyup) {
      #pragma unroll
      for (int r = 0; r < 16; ++r) { o0[r] *= alpha; o1[r] *= alpha; }
    }

    #pragma unroll
    for (int s = 0; s < 4; ++s) {
      bf16x8 pb  = *(const bf16x8*)&psw[l31 * 72 + s * 16 + q1 * 8];
      bf16x8 va0 = *(const bf16x8*)&vs[l31 * 72 + s * 16 + q1 * 8];
      bf16x8 va1 = *(const bf16x8*)&vs[(32 + l31) * 72 + s * 16 + q1 * 8];
      o0 = __builtin_amdgcn_mfma_f32_32x32x16_bf16(va0, pb, o0, 0, 0, 0);
      o1 = __builtin_amdgcn_mfma_f32_32x32x16_bf16(va1, pb, o1, 0, 0, 0);
    }
  }

  // epilogue: per-wave LDS transpose -> aoT[b][tok][h*64+d] bf16
  float inv = 1.0f / lrun;
  #pragma unroll
  for (int dm = 0; dm < 2; ++dm) {
    #pragma unroll
    for (int g = 0; g < 4; ++g) {
      ushort4 pk;
      if (dm == 0) {
        pk.x = f2bf(o0[4 * g + 0] * inv); pk.y = f2bf(o0[4 * g + 1] * inv);
        pk.z = f2bf(o0[4 * g + 2] * inv); pk.w = f2bf(o0[4 * g + 3] * inv);
      } else {
        pk.x = f2bf(o1[4 * g + 0] * inv); pk.y = f2bf(o1[4 * g + 1] * inv);
        pk.z = f2bf(o1[4 * g + 2] * inv); pk.w = f2bf(o1[4 * g + 3] * inv);
      }
      *(ushort4*)&psw[l31 * 72 + dm * 32 + g * 8 + q1 * 4] = pk;
    }
  }
  const size_t obase = (size_t)b * NN_TOK;
  #pragma unroll
  for (int it = 0; it < 4; ++it) {
    int idx = it * 64 + lane;
    int row = idx >> 3, ch = idx & 7;
    int tok = i0 + w * 32 + row;
    *(uint4*)&aoT[(obase + tok) * HID + h * DHEAD + ch * 8] =
        *(const uint4*)&psw[row * 72 + ch * 8];
  }
}

// ---------------------------------------------------------------------------
extern "C" void kernel_launch(void* const* d_in, const int* in_sizes, int n_in,
                              void* d_out, int out_size, void* d_ws, size_t ws_size,
                              hipStream_t stream) {
  const float* x     = (const float*)d_in[0];
  const float* gamma = (const float*)d_in[1];
  const float* beta  = (const float*)d_in[2];
  const float* wq    = (const float*)d_in[3];
  const float* bq    = (const float*)d_in[4];
  const float* wk    = (const float*)d_in[5];
  const float* bk    = (const float*)d_in[6];
  const float* wv    = (const float*)d_in[7];
  const float* bv    = (const float*)d_in[8];
  const float* wo    = (const float*)d_in[9];
  const float* bo    = (const float*)d_in[10];
  float* out = (float*)d_out;

  const size_t SZ = (size_t)BB * CC * NN_TOK;       // 4,194,304 elements
  const size_t WZ = (size_t)CC * HID;               // 262,144 elements
  unsigned short* xnb = (unsigned short*)d_ws;      // bf16 [b][c][tok]   8 MB
  unsigned short* xnT = xnb + SZ;                   // bf16 [b][tok][c]   8 MB
  unsigned short* qT  = xnT + SZ;                   // bf16 [b,h,tok,d]   8 MB
  unsigned short* kT  = qT + SZ;                    // 8 MB
  unsigned short* vB  = kT + SZ;                    // bf16 [b][c][tok]   8 MB
  unsigned short* aoT = vB + SZ;                    // bf16 [b][tok][hid] 8 MB
  unsigned short* wqb = aoT + SZ;                   // bf16 weights
  unsigned short* wkb = wqb + WZ;
  unsigned short* wvb = wkb + WZ;
  unsigned short* wob = wvb + WZ;

  wconv_kernel<<<dim3(128, 4), dim3(256), 0, stream>>>(
      wq, wk, wv, wo, wqb, wkb, wvb, wob);

  gn_kernel<<<dim3(BB * GROUPS), dim3(256), 0, stream>>>(x, gamma, beta, xnb);

  transpose_kernel<<<dim3(NN_TOK / 64, CC / 64, BB), dim3(256), 0, stream>>>(
      xnb, xnT);

  qkv_gemm_kernel<<<dim3(NN_TOK / 128, 12, BB), dim3(256), 0, stream>>>(
      xnT, wqb, wkb, wvb, bq, bk, bv, qT, kT, vB);

  attn_mfma_kernel<<<dim3(NN_TOK / 128, BB * HEADS), dim3(256), 0, stream>>>(
      qT, kT, vB, aoT);

  outproj_kernel<<<dim3(NN_TOK / 128, CC / 128, BB), dim3(256), 0, stream>>>(
      aoT, wob, bo, x, out);
}